// Round 8
// baseline (86.835 us; speedup 1.0000x reference)
//
#include <hip/hip_runtime.h>

#define K_ITERS 20
#define MU_CONST 0.05f
#define BN 128
#define YSTRIDE 24      // float stride between 16-float y slices (bank spread)

typedef float v4f __attribute__((ext_vector_type(4)));
typedef __attribute__((address_space(1))) const v4f gc4;   // global const float4
typedef __attribute__((address_space(1))) v4f g4;          // global float4

// DPP butterfly add step (pure VALU cross-lane; ctrl must be immediate).
template <int CTRL>
__device__ __forceinline__ float dpp_add(float v) {
    int x = __builtin_amdgcn_update_dpp(0, __float_as_int(v), CTRL, 0xF, 0xF, true);
    return v + __int_as_float(x);
}
// sum over the 8 lanes sharing a row-quad (lane bits [2:0] = col-group g)
__device__ __forceinline__ float reduce8(float v) {
    v = dpp_add<0xB1>(v);   // quad_perm xor1
    v = dpp_add<0x4E>(v);   // quad_perm xor2
    v = dpp_add<0x141>(v);  // row_half_mirror
    return v;
}

// One block per batch (4096 blocks). 256 threads, 4 blocks/CU.
// Block-level pipelining provides load/compute overlap (backfill).
// w is stream-once -> NON-TEMPORAL loads: bypass L1 line allocation so the
// 64-distinct-line load bursts aren't MSHR-throttled.
// Lane (wv,q,g): rows wv*32+q*4+{0..3}, cols g*16+{0..15} -> 16 float4 of w.
__global__ __launch_bounds__(256, 4) void nag_kernel(
    const float* __restrict__ w,
    const float* __restrict__ bvec,
    const float* __restrict__ s_ptr,
    float* __restrict__ out,
    int B)
{
    __shared__ __align__(16) float y_lds[2][8 * YSTRIDE];   // ping-pong y

    const int t  = threadIdx.x;       // 0..255
    const int wv = t >> 6;            // wave 0..3
    const int q  = (t >> 3) & 7;      // row-quad within wave
    const int g  = t & 7;             // col-group (16 cols)
    const int row0   = wv * 32 + q * 4;
    const int wslice = (row0 >> 4) * YSTRIDE + (q & 3) * 4;  // y write offset
    const int rbase  = g * YSTRIDE;                          // y read offset

    const int batch = blockIdx.x;

    // issue all global loads up front: 16x dwordx4 (w, nt) + 1x dwordx4 (b) + s
    v4f w4[4][4];
    const gc4* wp = (const gc4*)(w + (size_t)batch * (BN * BN)
                                   + (size_t)row0 * BN + g * 16);
#pragma unroll
    for (int rho = 0; rho < 4; ++rho)
#pragma unroll
        for (int k = 0; k < 4; ++k)
            w4[rho][k] = __builtin_nontemporal_load(&wp[rho * 32 + k]);

    const v4f br4 = *(const gc4*)(bvec + (size_t)batch * BN + row0);
    const float br_[4] = {br4.x, br4.y, br4.z, br4.w};

    const float s     = *s_ptr;
    const float sqms  = sqrtf(MU_CONST * s);
    const float alpha = (1.0f - sqms) / (1.0f + sqms);
    const float ap1   = 1.0f + alpha;

    // closed-form step 1 (y0 = 0): x1 = s*b, y1 = (1+alpha)*x1
    float xs[4], ys[4];
#pragma unroll
    for (int rho = 0; rho < 4; ++rho) {
        xs[rho] = s * br_[rho];
        ys[rho] = ap1 * xs[rho];
    }
    if (g == 0)
        *reinterpret_cast<v4f*>(&y_lds[0][wslice]) =
            (v4f){ys[0], ys[1], ys[2], ys[3]};
    __syncthreads();

#pragma unroll 2
    for (int it = 1; it < K_ITERS; ++it) {
        const float* yb = &y_lds[(it + 1) & 1][rbase];
        v4f yv[4];
#pragma unroll
        for (int k = 0; k < 4; ++k)
            yv[k] = *reinterpret_cast<const v4f*>(yb + k * 4);

#pragma unroll
        for (int rho = 0; rho < 4; ++rho) {
            float p = w4[rho][0].x * yv[0].x;
            p = fmaf(w4[rho][0].y, yv[0].y, p);
            p = fmaf(w4[rho][0].z, yv[0].z, p);
            p = fmaf(w4[rho][0].w, yv[0].w, p);
            p = fmaf(w4[rho][1].x, yv[1].x, p);
            p = fmaf(w4[rho][1].y, yv[1].y, p);
            p = fmaf(w4[rho][1].z, yv[1].z, p);
            p = fmaf(w4[rho][1].w, yv[1].w, p);
            p = fmaf(w4[rho][2].x, yv[2].x, p);
            p = fmaf(w4[rho][2].y, yv[2].y, p);
            p = fmaf(w4[rho][2].z, yv[2].z, p);
            p = fmaf(w4[rho][2].w, yv[2].w, p);
            p = fmaf(w4[rho][3].x, yv[3].x, p);
            p = fmaf(w4[rho][3].y, yv[3].y, p);
            p = fmaf(w4[rho][3].z, yv[3].z, p);
            p = fmaf(w4[rho][3].w, yv[3].w, p);
            const float d  = reduce8(p);           // full 128-col dot
            const float xn = fmaf(-s, d - br_[rho], ys[rho]);
            ys[rho] = fmaf(ap1, xn, -(alpha * xs[rho]));
            xs[rho] = xn;
        }

        if (it != K_ITERS - 1 && g == 0)
            *reinterpret_cast<v4f*>(&y_lds[it & 1][wslice]) =
                (v4f){ys[0], ys[1], ys[2], ys[3]};
        __syncthreads();
    }

    // outputs: x then y, each B*BN flat; rows row0..row0+3 contiguous (nt stores)
    const size_t ob = (size_t)batch * BN + row0;
    if (g == 0)
        __builtin_nontemporal_store((v4f){xs[0], xs[1], xs[2], xs[3]},
                                    (g4*)(out + ob));
    else if (g == 1)
        __builtin_nontemporal_store((v4f){ys[0], ys[1], ys[2], ys[3]},
                                    (g4*)(out + (size_t)B * BN + ob));
}

extern "C" void kernel_launch(void* const* d_in, const int* in_sizes, int n_in,
                              void* d_out, int out_size, void* d_ws, size_t ws_size,
                              hipStream_t stream) {
    const float* w = (const float*)d_in[0];
    const float* b = (const float*)d_in[1];
    const float* s = (const float*)d_in[2];
    float* out = (float*)d_out;
    const int B = in_sizes[1] / BN;    // 4096
    nag_kernel<<<dim3(B), dim3(256), 0, stream>>>(w, b, s, out, B);
}

// Round 9
// 60.969 us; speedup vs baseline: 1.4243x; 1.4243x over previous
//
#include <hip/hip_runtime.h>

#define K_ITERS 20
#define MU_CONST 0.05f
#define BN 128
#define YSTRIDE 24      // float stride between 16-float y slices (bank spread)

// HW_REG_HW_ID.WAVE_ID[3:0]: hwreg id=4, offset=0, width=4 -> (width-1)<<11 | off<<6 | id
#define HWID_WAVE_IMM ((3 << 11) | (0 << 6) | 4)

typedef float v4f __attribute__((ext_vector_type(4)));
typedef __attribute__((address_space(1))) const v4f gc4;   // global const float4
typedef __attribute__((address_space(1))) v4f g4;          // global float4

// DPP butterfly add step (pure VALU cross-lane; ctrl must be immediate).
template <int CTRL>
__device__ __forceinline__ float dpp_add(float v) {
    int x = __builtin_amdgcn_update_dpp(0, __float_as_int(v), CTRL, 0xF, 0xF, true);
    return v + __int_as_float(x);
}
// sum over the 8 lanes sharing a row-quad (lane bits [2:0] = col-group g)
__device__ __forceinline__ float reduce8(float v) {
    v = dpp_add<0xB1>(v);   // quad_perm xor1
    v = dpp_add<0x4E>(v);   // quad_perm xor2
    v = dpp_add<0x141>(v);  // row_half_mirror
    return v;
}

// One block per batch (4096 blocks). 256 threads, 4 blocks/CU.
// Phase-lock breaker: co-resident blocks (identified by HW wave-slot id) start
// staggered by ~2.4us (one block-load time) so one block is always loading
// while the others compute -> HBM port stays busy. First generation only;
// later generations inherit the stagger via retirement timing.
// Lane (wv,q,g): rows wv*32+q*4+{0..3}, cols g*16+{0..15} -> 16 float4 of w.
__global__ __launch_bounds__(256, 4) void nag_kernel(
    const float* __restrict__ w,
    const float* __restrict__ bvec,
    const float* __restrict__ s_ptr,
    float* __restrict__ out,
    int B)
{
    __shared__ __align__(16) float y_lds[2][8 * YSTRIDE];   // ping-pong y

    const int t  = threadIdx.x;       // 0..255
    const int wv = t >> 6;            // wave 0..3
    const int q  = (t >> 3) & 7;      // row-quad within wave
    const int g  = t & 7;             // col-group (16 cols)
    const int row0   = wv * 32 + q * 4;
    const int wslice = (row0 >> 4) * YSTRIDE + (q & 3) * 4;  // y write offset
    const int rbase  = g * YSTRIDE;                          // y read offset

    const int batch = blockIdx.x;

    // ---- start-stagger (first generation only) ----
    if (blockIdx.x < 1024) {
        const int slot = __builtin_amdgcn_s_getreg(HWID_WAVE_IMM) & 3;
#pragma unroll 1
        for (int i = 0; i < slot; ++i)
            asm volatile("s_sleep 90");   // ~5760 cycles = ~2.4 us each
    }

    // issue all global loads: 16x dwordx4 (w) + 1x dwordx4 (b) + s
    v4f w4[4][4];
    const gc4* wp = (const gc4*)(w + (size_t)batch * (BN * BN)
                                   + (size_t)row0 * BN + g * 16);
#pragma unroll
    for (int rho = 0; rho < 4; ++rho)
#pragma unroll
        for (int k = 0; k < 4; ++k)
            w4[rho][k] = wp[rho * 32 + k];

    const v4f br4 = *(const gc4*)(bvec + (size_t)batch * BN + row0);
    const float br_[4] = {br4.x, br4.y, br4.z, br4.w};

    const float s     = *s_ptr;
    const float sqms  = sqrtf(MU_CONST * s);
    const float alpha = (1.0f - sqms) / (1.0f + sqms);
    const float ap1   = 1.0f + alpha;

    // closed-form step 1 (y0 = 0): x1 = s*b, y1 = (1+alpha)*x1
    float xs[4], ys[4];
#pragma unroll
    for (int rho = 0; rho < 4; ++rho) {
        xs[rho] = s * br_[rho];
        ys[rho] = ap1 * xs[rho];
    }
    if (g == 0)
        *reinterpret_cast<v4f*>(&y_lds[0][wslice]) =
            (v4f){ys[0], ys[1], ys[2], ys[3]};
    __syncthreads();

#pragma unroll 2
    for (int it = 1; it < K_ITERS; ++it) {
        const float* yb = &y_lds[(it + 1) & 1][rbase];
        v4f yv[4];
#pragma unroll
        for (int k = 0; k < 4; ++k)
            yv[k] = *reinterpret_cast<const v4f*>(yb + k * 4);

#pragma unroll
        for (int rho = 0; rho < 4; ++rho) {
            float p = w4[rho][0].x * yv[0].x;
            p = fmaf(w4[rho][0].y, yv[0].y, p);
            p = fmaf(w4[rho][0].z, yv[0].z, p);
            p = fmaf(w4[rho][0].w, yv[0].w, p);
            p = fmaf(w4[rho][1].x, yv[1].x, p);
            p = fmaf(w4[rho][1].y, yv[1].y, p);
            p = fmaf(w4[rho][1].z, yv[1].z, p);
            p = fmaf(w4[rho][1].w, yv[1].w, p);
            p = fmaf(w4[rho][2].x, yv[2].x, p);
            p = fmaf(w4[rho][2].y, yv[2].y, p);
            p = fmaf(w4[rho][2].z, yv[2].z, p);
            p = fmaf(w4[rho][2].w, yv[2].w, p);
            p = fmaf(w4[rho][3].x, yv[3].x, p);
            p = fmaf(w4[rho][3].y, yv[3].y, p);
            p = fmaf(w4[rho][3].z, yv[3].z, p);
            p = fmaf(w4[rho][3].w, yv[3].w, p);
            const float d  = reduce8(p);           // full 128-col dot
            const float xn = fmaf(-s, d - br_[rho], ys[rho]);
            ys[rho] = fmaf(ap1, xn, -(alpha * xs[rho]));
            xs[rho] = xn;
        }

        if (it != K_ITERS - 1 && g == 0)
            *reinterpret_cast<v4f*>(&y_lds[it & 1][wslice]) =
                (v4f){ys[0], ys[1], ys[2], ys[3]};
        __syncthreads();
    }

    // outputs: x then y, each B*BN flat; rows row0..row0+3 contiguous
    const size_t ob = (size_t)batch * BN + row0;
    if (g == 0)
        *(g4*)(out + ob) = (v4f){xs[0], xs[1], xs[2], xs[3]};
    else if (g == 1)
        *(g4*)(out + (size_t)B * BN + ob) = (v4f){ys[0], ys[1], ys[2], ys[3]};
}

extern "C" void kernel_launch(void* const* d_in, const int* in_sizes, int n_in,
                              void* d_out, int out_size, void* d_ws, size_t ws_size,
                              hipStream_t stream) {
    const float* w = (const float*)d_in[0];
    const float* b = (const float*)d_in[1];
    const float* s = (const float*)d_in[2];
    float* out = (float*)d_out;
    const int B = in_sizes[1] / BN;    // 4096
    nag_kernel<<<dim3(B), dim3(256), 0, stream>>>(w, b, s, out, B);
}